// Round 2
// baseline (7069.652 us; speedup 1.0000x reference)
//
#include <hip/hip_runtime.h>
#include <hip/hip_fp16.h>

#define N_NODES 100000
#define N_EDGES 1600000
#define E_PAD   (N_EDGES + 8 * 256)

// ===================================================================
// NEW PATH: CSR + octant-bucketed messages (no float atomics)
// ===================================================================

__device__ __forceinline__ void pseudo_to_basis(float p0, float p1, float p2,
                                                int& oct, float* w) {
    float v0 = p0 * 2.0f, v1 = p1 * 2.0f, v2 = p2 * 2.0f;
    int i0 = v0 >= 1.0f, i1 = v1 >= 1.0f, i2 = v2 >= 1.0f;
    float fr0 = v0 - (float)i0, fr1 = v1 - (float)i1, fr2 = v2 - (float)i2;
    oct = i0 + 2 * i1 + 4 * i2;
    float a0[2] = {1.0f - fr0, fr0};
    float a1[2] = {1.0f - fr1, fr1};
    float a2[2] = {1.0f - fr2, fr2};
    #pragma unroll
    for (int b = 0; b < 8; ++b)
        w[b] = a0[b & 1] * a1[(b >> 1) & 1] * a2[(b >> 2) & 1];
}

__global__ __launch_bounds__(256) void count_k(const int* __restrict__ dst,
                                               const float* __restrict__ pseudo,
                                               int* __restrict__ cnt,
                                               int* __restrict__ octcnt) {
    __shared__ int loct[8];
    if (threadIdx.x < 8) loct[threadIdx.x] = 0;
    __syncthreads();
    int e = blockIdx.x * 256 + threadIdx.x;
    if (e < N_EDGES) {
        atomicAdd(&cnt[dst[e]], 1);
        size_t pb = (size_t)e * 3;
        int oct; float w[8];
        pseudo_to_basis(pseudo[pb], pseudo[pb + 1], pseudo[pb + 2], oct, w);
        atomicAdd(&loct[oct], 1);
    }
    __syncthreads();
    if (threadIdx.x < 8) atomicAdd(&octcnt[threadIdx.x], loct[threadIdx.x]);
}

__global__ __launch_bounds__(1024) void scan_k(const int* __restrict__ cnt,
                                               int* __restrict__ rowptr,
                                               const int* __restrict__ octcnt,
                                               int* __restrict__ octbase) {
    const int CH = (N_NODES + 1023) / 1024;
    __shared__ int ssum[1024];
    int t = threadIdx.x;
    int beg = t * CH, end = min(beg + CH, N_NODES);
    int s = 0;
    for (int i = beg; i < end; ++i) s += cnt[i];
    ssum[t] = s;
    __syncthreads();
    for (int off = 1; off < 1024; off <<= 1) {
        int v = (t >= off) ? ssum[t - off] : 0;
        __syncthreads();
        ssum[t] += v;
        __syncthreads();
    }
    int run = (t == 0) ? 0 : ssum[t - 1];
    for (int i = beg; i < end; ++i) { rowptr[i] = run; run += cnt[i]; }
    if (t == 1023) rowptr[N_NODES] = ssum[1023];
    if (t == 0) {
        int b = 0;
        #pragma unroll
        for (int g = 0; g < 8; ++g) {
            octbase[g] = b;
            b += ((octcnt[g] + 255) / 256) * 256;
        }
        octbase[8] = b;
    }
}

__global__ __launch_bounds__(256) void scatter_k(const int* __restrict__ src,
                                                 const int* __restrict__ dst,
                                                 const float* __restrict__ pseudo,
                                                 const int* __restrict__ rowptr,
                                                 int* __restrict__ cnt2,
                                                 const int* __restrict__ octbase,
                                                 int* __restrict__ octoff,
                                                 int* __restrict__ oSrc,
                                                 int* __restrict__ oDst,
                                                 __half* __restrict__ oW8) {
    __shared__ int lcnt[8];
    __shared__ int lbase[8];
    if (threadIdx.x < 8) lcnt[threadIdx.x] = 0;
    __syncthreads();
    int e = blockIdx.x * 256 + threadIdx.x;
    int oct = 0, rank = 0;
    float w[8];
    if (e < N_EDGES) {
        size_t pb = (size_t)e * 3;
        pseudo_to_basis(pseudo[pb], pseudo[pb + 1], pseudo[pb + 2], oct, w);
        rank = atomicAdd(&lcnt[oct], 1);
    }
    __syncthreads();
    if (threadIdx.x < 8) lbase[threadIdx.x] = atomicAdd(&octoff[threadIdx.x], lcnt[threadIdx.x]);
    __syncthreads();
    if (e < N_EDGES) {
        int d = dst[e];
        int p = rowptr[d] + atomicAdd(&cnt2[d], 1);
        int slot = octbase[oct] + lbase[oct] + rank;
        oSrc[slot] = src[e];
        oDst[slot] = p + 1;                 // row 0 of m is the trash row
        union { int4 v; __half h[8]; } su;
        #pragma unroll
        for (int b = 0; b < 8; ++b) su.h[b] = __float2half(w[b]);
        ((int4*)oW8)[slot] = su.v;
    }
}

// message kernel: one thread per octant-sorted edge slot; W indices wave-uniform
template<int Fin, int Fout>
__global__ __launch_bounds__(256) void msg_k(const float* __restrict__ h,
                                             const int* __restrict__ oSrc,
                                             const int* __restrict__ oDst,
                                             const __half* __restrict__ oW8,
                                             const int* __restrict__ octbase,
                                             const float* __restrict__ W,
                                             float* __restrict__ m) {
    int base = blockIdx.x * 256;
    int total = octbase[8];
    if (base >= total) return;
    int g = 0;
    #pragma unroll
    for (int q = 1; q < 8; ++q)
        if (base >= octbase[q]) g = q;
    g = __builtin_amdgcn_readfirstlane(g);
    const int i0 = g & 1, i1 = (g >> 1) & 1, i2 = (g >> 2) & 1;
    const int base_idx = i0 + 3 * i1 + 9 * i2;

    int j = base + threadIdx.x;
    int s = oSrc[j];
    int dp = oDst[j];

    union { int4 v; __half2 h2[4]; } u;
    u.v = ((const int4*)oW8)[j];
    float w[8];
    #pragma unroll
    for (int q = 0; q < 4; ++q) {
        float2 f = __half22float2(u.h2[q]);
        w[2 * q] = f.x; w[2 * q + 1] = f.y;
    }

    float x[Fin];
    if constexpr (Fin % 4 == 0) {
        const float4* xv = reinterpret_cast<const float4*>(h + (size_t)s * Fin);
        #pragma unroll
        for (int f = 0; f < Fin / 4; ++f) {
            float4 t = xv[f];
            x[4*f+0] = t.x; x[4*f+1] = t.y; x[4*f+2] = t.z; x[4*f+3] = t.w;
        }
    } else {
        #pragma unroll
        for (int f = 0; f < Fin; ++f) x[f] = h[(size_t)s * Fin + f];
    }

    float z[Fout];
    #pragma unroll
    for (int o = 0; o < Fout; ++o) z[o] = 0.0f;

    #pragma unroll
    for (int b = 0; b < 8; ++b) {
        const int idx = base_idx + (b & 1) + 3 * ((b >> 1) & 1) + 9 * ((b >> 2) & 1); // uniform
        const float* __restrict__ wp = W + (size_t)idx * (Fin * Fout);
        float wb = w[b];
        #pragma unroll
        for (int f = 0; f < Fin; ++f) {
            float a = wb * x[f];
            #pragma unroll
            for (int o = 0; o < Fout; ++o) z[o] = fmaf(a, wp[f * Fout + o], z[o]);
        }
    }

    float* mp = m + (size_t)dp * Fout;
    if constexpr (Fout % 4 == 0) {
        #pragma unroll
        for (int o = 0; o < Fout / 4; ++o) {
            float4 t; t.x = z[4*o]; t.y = z[4*o+1]; t.z = z[4*o+2]; t.w = z[4*o+3];
            ((float4*)mp)[o] = t;
        }
    } else {
        #pragma unroll
        for (int o = 0; o < Fout; ++o) mp[o] = z[o];
    }
}

// gather kernel: one thread per node; sums its m rows, fuses root/bias/ELU
template<int Fin, int Fout>
__global__ __launch_bounds__(256) void gather_k(const float* __restrict__ hin,
                                                const float* __restrict__ m,
                                                const int* __restrict__ rowptr,
                                                const float* __restrict__ root,
                                                const float* __restrict__ bias,
                                                float* __restrict__ hout) {
    int n = blockIdx.x * 256 + threadIdx.x;
    if (n >= N_NODES) return;

    float acc[Fout];
    #pragma unroll
    for (int o = 0; o < Fout; ++o) acc[o] = bias[o];

    float x[Fin];
    if constexpr (Fin % 4 == 0) {
        const float4* xv = reinterpret_cast<const float4*>(hin + (size_t)n * Fin);
        #pragma unroll
        for (int f = 0; f < Fin / 4; ++f) {
            float4 t = xv[f];
            x[4*f+0] = t.x; x[4*f+1] = t.y; x[4*f+2] = t.z; x[4*f+3] = t.w;
        }
    } else {
        #pragma unroll
        for (int f = 0; f < Fin; ++f) x[f] = hin[(size_t)n * Fin + f];
    }
    #pragma unroll
    for (int f = 0; f < Fin; ++f) {
        #pragma unroll
        for (int o = 0; o < Fout; ++o) acc[o] = fmaf(x[f], root[f * Fout + o], acc[o]);
    }

    int r0 = rowptr[n], r1 = rowptr[n + 1];
    for (int j = r0; j < r1; ++j) {
        const float* mp = m + (size_t)(j + 1) * Fout;
        if constexpr (Fout % 4 == 0) {
            #pragma unroll
            for (int o = 0; o < Fout / 4; ++o) {
                float4 t = ((const float4*)mp)[o];
                acc[4*o]   += t.x; acc[4*o+1] += t.y;
                acc[4*o+2] += t.z; acc[4*o+3] += t.w;
            }
        } else {
            #pragma unroll
            for (int o = 0; o < Fout; ++o) acc[o] += mp[o];
        }
    }

    #pragma unroll
    for (int o = 0; o < Fout; ++o) {
        float t = acc[o];
        hout[(size_t)n * Fout + o] = t > 0.0f ? t : expm1f(t);
    }
}

// ===================================================================
// FALLBACK PATH (round-0 atomic version) — used if ws too small
// ===================================================================

template<int Fin, int Fout>
__global__ __launch_bounds__(256) void init_out_k(const float* __restrict__ h,
                                                  const float* __restrict__ root,
                                                  const float* __restrict__ bias,
                                                  float* __restrict__ out) {
    int n = blockIdx.x * 256 + threadIdx.x;
    if (n >= N_NODES) return;
    float xr[Fin];
    #pragma unroll
    for (int f = 0; f < Fin; ++f) xr[f] = h[(size_t)n * Fin + f];
    float z[Fout];
    #pragma unroll
    for (int o = 0; o < Fout; ++o) z[o] = bias[o];
    #pragma unroll
    for (int f = 0; f < Fin; ++f)
        #pragma unroll
        for (int o = 0; o < Fout; ++o) z[o] += xr[f] * root[f * Fout + o];
    #pragma unroll
    for (int o = 0; o < Fout; ++o) out[(size_t)n * Fout + o] = z[o];
}

template<int Fin, int Fout>
__global__ __launch_bounds__(256) void edge_k(const float* __restrict__ h,
                                              const int* __restrict__ src,
                                              const int* __restrict__ dst,
                                              const float* __restrict__ pseudo,
                                              const float* __restrict__ W,
                                              float* __restrict__ out) {
    constexpr int KFF = Fin * Fout;
    constexpr int STRIDE = KFF + 1;
    __shared__ float sW[27 * STRIDE];
    for (int i = threadIdx.x; i < 27 * KFF; i += 256) {
        int k = i / KFF;
        sW[k * STRIDE + (i - k * KFF)] = W[i];
    }
    __syncthreads();
    int e = blockIdx.x * 256 + threadIdx.x;
    if (e >= N_EDGES) return;
    int s = src[e], d = dst[e];
    size_t pb = (size_t)e * 3;
    int oct; float w[8];
    pseudo_to_basis(pseudo[pb], pseudo[pb+1], pseudo[pb+2], oct, w);
    int i0 = oct & 1, i1 = (oct >> 1) & 1, i2 = (oct >> 2) & 1;
    float xr[Fin];
    #pragma unroll
    for (int f = 0; f < Fin; ++f) xr[f] = h[(size_t)s * Fin + f];
    float z[Fout];
    #pragma unroll
    for (int o = 0; o < Fout; ++o) z[o] = 0.0f;
    #pragma unroll
    for (int b = 0; b < 8; ++b) {
        int idx = (i0 + (b & 1)) + 3 * (i1 + ((b >> 1) & 1)) + 9 * (i2 + ((b >> 2) & 1));
        const float* wp = &sW[idx * STRIDE];
        #pragma unroll
        for (int f = 0; f < Fin; ++f) {
            float a = w[b] * xr[f];
            #pragma unroll
            for (int o = 0; o < Fout; ++o) z[o] += a * wp[f * Fout + o];
        }
    }
    float* op = out + (size_t)d * Fout;
    #pragma unroll
    for (int o = 0; o < Fout; ++o) atomicAdd(&op[o], z[o]);
}

__global__ __launch_bounds__(256) void elu_k(float* __restrict__ p, int total) {
    int i = blockIdx.x * 256 + threadIdx.x;
    if (i < total) {
        float t = p[i];
        p[i] = t > 0.0f ? t : expm1f(t);
    }
}

// ===================================================================
// host
// ===================================================================

template<int Fin, int Fout>
static void run_layer_new(const float* hin, float* hout,
                          const float* W, const float* root, const float* bias,
                          const int* oSrc, const int* oDst, const __half* oW8,
                          const int* octbase, const int* rowptr, float* m,
                          hipStream_t stream) {
    msg_k<Fin, Fout><<<(E_PAD + 255) / 256, 256, 0, stream>>>(hin, oSrc, oDst, oW8, octbase, W, m);
    gather_k<Fin, Fout><<<(N_NODES + 255) / 256, 256, 0, stream>>>(hin, m, rowptr, root, bias, hout);
}

template<int Fin, int Fout>
static void run_layer_old(const float* hin, float* hout,
                          const float* W, const float* root, const float* bias,
                          const int* src, const int* dst, const float* pseudo,
                          hipStream_t stream) {
    init_out_k<Fin, Fout><<<(N_NODES + 255) / 256, 256, 0, stream>>>(hin, root, bias, hout);
    edge_k<Fin, Fout><<<(N_EDGES + 255) / 256, 256, 0, stream>>>(hin, src, dst, pseudo, W, hout);
    int total = N_NODES * Fout;
    elu_k<<<(total + 255) / 256, 256, 0, stream>>>(hout, total);
}

extern "C" void kernel_launch(void* const* d_in, const int* in_sizes, int n_in,
                              void* d_out, int out_size, void* d_ws, size_t ws_size,
                              hipStream_t stream) {
    const float* x      = (const float*)d_in[0];
    const int*   ei     = (const int*)d_in[1];
    const float* pseudo = (const float*)d_in[2];
    const int* src = ei;
    const int* dst = ei + N_EDGES;

    const float* W[6]; const float* R[6]; const float* B[6];
    for (int i = 0; i < 6; ++i) {
        W[i] = (const float*)d_in[3 + 3 * i];
        R[i] = (const float*)d_in[4 + 3 * i];
        B[i] = (const float*)d_in[5 + 3 * i];
    }

    char* ws = (char*)d_ws;
    size_t off = 0;
    auto alloc = [&](size_t bytes) { size_t c = off; off = (off + bytes + 255) & ~(size_t)255; return c; };

    size_t o_hA   = alloc((size_t)N_NODES * 32 * 4);
    size_t o_hB   = alloc((size_t)N_NODES * 32 * 4);
    size_t o_rp   = alloc((size_t)(N_NODES + 1) * 4);
    size_t o_meta = alloc((size_t)(2 * N_NODES + 16) * 4);  // cnt, cnt2, octcnt[8], octoff[8]
    size_t o_ob   = alloc(9 * 4);                            // octbase
    size_t o_src  = alloc((size_t)E_PAD * 4);
    size_t o_dst  = alloc((size_t)E_PAD * 4);
    size_t o_w8   = alloc((size_t)E_PAD * 16);
    size_t o_m    = alloc((size_t)(N_EDGES + 1) * 32 * 4);
    size_t needed = off;

    float* out = (float*)d_out;

    if (needed <= ws_size) {
        float* hA     = (float*)(ws + o_hA);
        float* hB     = (float*)(ws + o_hB);
        int*   rowptr = (int*)(ws + o_rp);
        int*   cnt    = (int*)(ws + o_meta);
        int*   cnt2   = cnt + N_NODES;
        int*   octcnt = cnt2 + N_NODES;
        int*   octoff = octcnt + 8;
        int*   octbase= (int*)(ws + o_ob);
        int*   oSrc   = (int*)(ws + o_src);
        int*   oDst   = (int*)(ws + o_dst);
        __half* oW8   = (__half*)(ws + o_w8);
        float* m      = (float*)(ws + o_m);

        // zero: counters block, and the octant-sorted arrays (covers dummy slots)
        hipMemsetAsync(cnt, 0, (size_t)(2 * N_NODES + 16) * 4, stream);
        hipMemsetAsync(ws + o_src, 0, (o_w8 + (size_t)E_PAD * 16) - o_src, stream);

        count_k<<<(N_EDGES + 255) / 256, 256, 0, stream>>>(dst, pseudo, cnt, octcnt);
        scan_k<<<1, 1024, 0, stream>>>(cnt, rowptr, octcnt, octbase);
        scatter_k<<<(N_EDGES + 255) / 256, 256, 0, stream>>>(src, dst, pseudo, rowptr, cnt2,
                                                             octbase, octoff, oSrc, oDst, oW8);

        run_layer_new<1, 8>  (x,  hA, W[0], R[0], B[0], oSrc, oDst, oW8, octbase, rowptr, m, stream);
        run_layer_new<8, 16> (hA, hB, W[1], R[1], B[1], oSrc, oDst, oW8, octbase, rowptr, m, stream);
        run_layer_new<16, 32>(hB, hA, W[2], R[2], B[2], oSrc, oDst, oW8, octbase, rowptr, m, stream);
        run_layer_new<32, 16>(hA, hB, W[3], R[3], B[3], oSrc, oDst, oW8, octbase, rowptr, m, stream);
        run_layer_new<16, 8> (hB, hA, W[4], R[4], B[4], oSrc, oDst, oW8, octbase, rowptr, m, stream);
        run_layer_new<8, 1>  (hA, out, W[5], R[5], B[5], oSrc, oDst, oW8, octbase, rowptr, m, stream);
    } else {
        float* hA = (float*)ws;
        float* hB = hA + (size_t)N_NODES * 32;
        run_layer_old<1, 8>  (x,  hA, W[0], R[0], B[0], src, dst, pseudo, stream);
        run_layer_old<8, 16> (hA, hB, W[1], R[1], B[1], src, dst, pseudo, stream);
        run_layer_old<16, 32>(hB, hA, W[2], R[2], B[2], src, dst, pseudo, stream);
        run_layer_old<32, 16>(hA, hB, W[3], R[3], B[3], src, dst, pseudo, stream);
        run_layer_old<16, 8> (hB, hA, W[4], R[4], B[4], src, dst, pseudo, stream);
        run_layer_old<8, 1>  (hA, out, W[5], R[5], B[5], src, dst, pseudo, stream);
    }
}

// Round 3
// 1112.055 us; speedup vs baseline: 6.3573x; 6.3573x over previous
//
#include <hip/hip_runtime.h>
#include <hip/hip_fp16.h>

#define N_NODES 100000
#define N_EDGES 1600000
#define E_PAD   (N_EDGES + 8 * 256)
#define GRID_E  (E_PAD / 256)

// ===================================================================
// helpers
// ===================================================================

__device__ __forceinline__ void pseudo_to_of(float p0, float p1, float p2,
                                             int& oct, float& fr0, float& fr1, float& fr2) {
    float v0 = p0 * 2.0f, v1 = p1 * 2.0f, v2 = p2 * 2.0f;
    int i0 = v0 >= 1.0f, i1 = v1 >= 1.0f, i2 = v2 >= 1.0f;
    fr0 = v0 - (float)i0; fr1 = v1 - (float)i1; fr2 = v2 - (float)i2;
    oct = i0 + 2 * i1 + 4 * i2;
}

template<int Fin>
__device__ __forceinline__ void loadx(const float* __restrict__ hp, float* x) {
    if constexpr (Fin % 4 == 0) {
        const float4* xv = reinterpret_cast<const float4*>(hp);
        #pragma unroll
        for (int f = 0; f < Fin / 4; ++f) {
            float4 t = xv[f];
            x[4*f+0] = t.x; x[4*f+1] = t.y; x[4*f+2] = t.z; x[4*f+3] = t.w;
        }
    } else {
        #pragma unroll
        for (int f = 0; f < Fin; ++f) x[f] = hp[f];
    }
}

template<int CH>
__device__ __forceinline__ void vstore(float* __restrict__ p, const float* z) {
    if constexpr (CH % 4 == 0) {
        #pragma unroll
        for (int o = 0; o < CH / 4; ++o) {
            float4 t; t.x = z[4*o]; t.y = z[4*o+1]; t.z = z[4*o+2]; t.w = z[4*o+3];
            ((float4*)p)[o] = t;
        }
    } else if constexpr (CH % 2 == 0) {
        #pragma unroll
        for (int o = 0; o < CH / 2; ++o) {
            float2 t; t.x = z[2*o]; t.y = z[2*o+1];
            ((float2*)p)[o] = t;
        }
    } else {
        #pragma unroll
        for (int o = 0; o < CH; ++o) p[o] = z[o];
    }
}

template<int CH>
__device__ __forceinline__ void vaccum(float* acc, const float* __restrict__ p) {
    if constexpr (CH % 4 == 0) {
        #pragma unroll
        for (int o = 0; o < CH / 4; ++o) {
            float4 t = ((const float4*)p)[o];
            acc[4*o] += t.x; acc[4*o+1] += t.y; acc[4*o+2] += t.z; acc[4*o+3] += t.w;
        }
    } else if constexpr (CH % 2 == 0) {
        #pragma unroll
        for (int o = 0; o < CH / 2; ++o) {
            float2 t = ((const float2*)p)[o];
            acc[2*o] += t.x; acc[2*o+1] += t.y;
        }
    } else {
        #pragma unroll
        for (int o = 0; o < CH; ++o) acc[o] += p[o];
    }
}

// ===================================================================
// setup kernels: CSR by dst + octant bucketing
// ===================================================================

__global__ __launch_bounds__(256) void count_k(const int* __restrict__ dst,
                                               const float* __restrict__ pseudo,
                                               int* __restrict__ cnt,
                                               int* __restrict__ octcnt) {
    __shared__ int loct[8];
    if (threadIdx.x < 8) loct[threadIdx.x] = 0;
    __syncthreads();
    int e = blockIdx.x * 256 + threadIdx.x;
    if (e < N_EDGES) {
        atomicAdd(&cnt[dst[e]], 1);
        size_t pb = (size_t)e * 3;
        int oct; float a, b, c;
        pseudo_to_of(pseudo[pb], pseudo[pb + 1], pseudo[pb + 2], oct, a, b, c);
        atomicAdd(&loct[oct], 1);
    }
    __syncthreads();
    if (threadIdx.x < 8) atomicAdd(&octcnt[threadIdx.x], loct[threadIdx.x]);
}

__global__ __launch_bounds__(1024) void scan_k(const int* __restrict__ cnt,
                                               int* __restrict__ rowptr,
                                               const int* __restrict__ octcnt,
                                               int* __restrict__ octbase) {
    const int CHK = (N_NODES + 1023) / 1024;
    __shared__ int ssum[1024];
    int t = threadIdx.x;
    int beg = t * CHK, end = min(beg + CHK, N_NODES);
    int s = 0;
    for (int i = beg; i < end; ++i) s += cnt[i];
    ssum[t] = s;
    __syncthreads();
    for (int off = 1; off < 1024; off <<= 1) {
        int v = (t >= off) ? ssum[t - off] : 0;
        __syncthreads();
        ssum[t] += v;
        __syncthreads();
    }
    int run = (t == 0) ? 0 : ssum[t - 1];
    for (int i = beg; i < end; ++i) { rowptr[i] = run; run += cnt[i]; }
    if (t == 1023) rowptr[N_NODES] = ssum[1023];
    if (t == 0) {
        int b = 0;
        #pragma unroll
        for (int g = 0; g < 8; ++g) {
            octbase[g] = b;
            b += ((octcnt[g] + 255) / 256) * 256;
        }
        octbase[8] = b;
    }
}

__global__ __launch_bounds__(256) void scatter_k(const int* __restrict__ src,
                                                 const int* __restrict__ dst,
                                                 const float* __restrict__ pseudo,
                                                 const int* __restrict__ rowptr,
                                                 int* __restrict__ cnt2,
                                                 const int* __restrict__ octbase,
                                                 int* __restrict__ octoff,
                                                 int* __restrict__ oSrc,
                                                 int* __restrict__ oDst,
                                                 uint2* __restrict__ oF3) {
    __shared__ int lcnt[8];
    __shared__ int lbase[8];
    if (threadIdx.x < 8) lcnt[threadIdx.x] = 0;
    __syncthreads();
    int e = blockIdx.x * 256 + threadIdx.x;
    int oct = 0, rank = 0;
    float fr0 = 0.f, fr1 = 0.f, fr2 = 0.f;
    if (e < N_EDGES) {
        size_t pb = (size_t)e * 3;
        pseudo_to_of(pseudo[pb], pseudo[pb + 1], pseudo[pb + 2], oct, fr0, fr1, fr2);
        rank = atomicAdd(&lcnt[oct], 1);
    }
    __syncthreads();
    if (threadIdx.x < 8) lbase[threadIdx.x] = atomicAdd(&octoff[threadIdx.x], lcnt[threadIdx.x]);
    __syncthreads();
    if (e < N_EDGES) {
        int d = dst[e];
        int p = rowptr[d] + atomicAdd(&cnt2[d], 1);
        int slot = octbase[oct] + lbase[oct] + rank;
        oSrc[slot] = src[e];
        oDst[slot] = p + 1;                 // m row 0 is the trash row
        union { uint2 v; __half h[4]; } su;
        su.h[0] = __float2half(fr0);
        su.h[1] = __float2half(fr1);
        su.h[2] = __float2half(fr2);
        su.h[3] = __float2half(0.0f);
        oF3[slot] = su.v;
    }
}

// ===================================================================
// msg kernel: octant-sorted edges, wave-uniform W pointers (scalar loads)
// computes columns [coff, coff+CH) of the per-edge message
// ===================================================================

template<int Fin, int Fout, int CH>
__global__ __launch_bounds__(256) void msg_k(const float* __restrict__ h,
                                             const int* __restrict__ oSrc,
                                             const int* __restrict__ oDst,
                                             const uint2* __restrict__ oF3,
                                             const int* __restrict__ octbase,
                                             const float* __restrict__ W,
                                             float* __restrict__ m,
                                             int coff) {
    int base = blockIdx.x * 256;
    if (base >= octbase[8]) return;
    int g = 0;
    #pragma unroll
    for (int q = 1; q < 8; ++q)
        if (base >= octbase[q]) g = q;
    g = __builtin_amdgcn_readfirstlane(g);
    const int bidx = (g & 1) + 3 * ((g >> 1) & 1) + 9 * ((g >> 2) & 1);

    int j = base + threadIdx.x;
    int s  = oSrc[j];
    int dp = oDst[j];

    union { uint2 v; __half hh[4]; } u;
    u.v = oF3[j];
    float fr0 = __half2float(u.hh[0]);
    float fr1 = __half2float(u.hh[1]);
    float fr2 = __half2float(u.hh[2]);
    float a0[2] = {1.0f - fr0, fr0};
    float a1[2] = {1.0f - fr1, fr1};
    float a2[2] = {1.0f - fr2, fr2};
    float w[8];
    #pragma unroll
    for (int b = 0; b < 8; ++b)
        w[b] = a0[b & 1] * a1[(b >> 1) & 1] * a2[(b >> 2) & 1];

    float x[Fin];
    loadx<Fin>(h + (size_t)s * Fin, x);

    float z[CH];
    #pragma unroll
    for (int o = 0; o < CH; ++o) z[o] = 0.0f;

    #pragma unroll
    for (int b = 0; b < 8; ++b) {
        const int idx = bidx + (b & 1) + 3 * ((b >> 1) & 1) + 9 * ((b >> 2) & 1); // uniform
        const float* __restrict__ wp = W + (size_t)idx * (Fin * Fout) + coff;
        float wb = w[b];
        #pragma unroll
        for (int f = 0; f < Fin; ++f) {
            float a = wb * x[f];
            #pragma unroll
            for (int o = 0; o < CH; ++o) z[o] = fmaf(a, wp[f * Fout + o], z[o]);
        }
    }

    vstore<CH>(m + (size_t)dp * CH, z);
}

// ===================================================================
// gather kernel: per-node CSR sum + root + bias + ELU, columns [coff, coff+CH)
// ===================================================================

template<int Fin, int Fout, int CH>
__global__ __launch_bounds__(256) void gather_k(const float* __restrict__ hin,
                                                const float* __restrict__ m,
                                                const int* __restrict__ rowptr,
                                                const float* __restrict__ root,
                                                const float* __restrict__ bias,
                                                float* __restrict__ hout,
                                                int coff) {
    int n = blockIdx.x * 256 + threadIdx.x;
    if (n >= N_NODES) return;

    float acc[CH];
    #pragma unroll
    for (int o = 0; o < CH; ++o) acc[o] = bias[coff + o];

    float x[Fin];
    loadx<Fin>(hin + (size_t)n * Fin, x);
    #pragma unroll
    for (int f = 0; f < Fin; ++f) {
        #pragma unroll
        for (int o = 0; o < CH; ++o)
            acc[o] = fmaf(x[f], root[f * Fout + coff + o], acc[o]);
    }

    int r0 = rowptr[n], r1 = rowptr[n + 1];
    for (int j = r0; j < r1; ++j)
        vaccum<CH>(acc, m + (size_t)(j + 1) * CH);

    #pragma unroll
    for (int o = 0; o < CH; ++o) {
        float t = acc[o];
        hout[(size_t)n * Fout + coff + o] = t > 0.0f ? t : expm1f(t);
    }
}

// ===================================================================
// FALLBACK PATH (atomic) — only if workspace is tiny
// ===================================================================

template<int Fin, int Fout>
__global__ __launch_bounds__(256) void init_out_k(const float* __restrict__ h,
                                                  const float* __restrict__ root,
                                                  const float* __restrict__ bias,
                                                  float* __restrict__ out) {
    int n = blockIdx.x * 256 + threadIdx.x;
    if (n >= N_NODES) return;
    float xr[Fin];
    #pragma unroll
    for (int f = 0; f < Fin; ++f) xr[f] = h[(size_t)n * Fin + f];
    float z[Fout];
    #pragma unroll
    for (int o = 0; o < Fout; ++o) z[o] = bias[o];
    #pragma unroll
    for (int f = 0; f < Fin; ++f)
        #pragma unroll
        for (int o = 0; o < Fout; ++o) z[o] += xr[f] * root[f * Fout + o];
    #pragma unroll
    for (int o = 0; o < Fout; ++o) out[(size_t)n * Fout + o] = z[o];
}

template<int Fin, int Fout>
__global__ __launch_bounds__(256) void edge_k(const float* __restrict__ h,
                                              const int* __restrict__ src,
                                              const int* __restrict__ dst,
                                              const float* __restrict__ pseudo,
                                              const float* __restrict__ W,
                                              float* __restrict__ out) {
    constexpr int KFF = Fin * Fout;
    constexpr int STRIDE = KFF + 1;
    __shared__ float sW[27 * STRIDE];
    for (int i = threadIdx.x; i < 27 * KFF; i += 256) {
        int k = i / KFF;
        sW[k * STRIDE + (i - k * KFF)] = W[i];
    }
    __syncthreads();
    int e = blockIdx.x * 256 + threadIdx.x;
    if (e >= N_EDGES) return;
    int s = src[e], d = dst[e];
    size_t pb = (size_t)e * 3;
    int oct; float fr0, fr1, fr2;
    pseudo_to_of(pseudo[pb], pseudo[pb+1], pseudo[pb+2], oct, fr0, fr1, fr2);
    int i0 = oct & 1, i1 = (oct >> 1) & 1, i2 = (oct >> 2) & 1;
    float a0[2] = {1.0f - fr0, fr0};
    float a1[2] = {1.0f - fr1, fr1};
    float a2[2] = {1.0f - fr2, fr2};
    float xr[Fin];
    #pragma unroll
    for (int f = 0; f < Fin; ++f) xr[f] = h[(size_t)s * Fin + f];
    float z[Fout];
    #pragma unroll
    for (int o = 0; o < Fout; ++o) z[o] = 0.0f;
    #pragma unroll
    for (int b = 0; b < 8; ++b) {
        int idx = (i0 + (b & 1)) + 3 * (i1 + ((b >> 1) & 1)) + 9 * (i2 + ((b >> 2) & 1));
        float wb = a0[b & 1] * a1[(b >> 1) & 1] * a2[(b >> 2) & 1];
        const float* wp = &sW[idx * STRIDE];
        #pragma unroll
        for (int f = 0; f < Fin; ++f) {
            float a = wb * xr[f];
            #pragma unroll
            for (int o = 0; o < Fout; ++o) z[o] += a * wp[f * Fout + o];
        }
    }
    float* op = out + (size_t)d * Fout;
    #pragma unroll
    for (int o = 0; o < Fout; ++o) atomicAdd(&op[o], z[o]);
}

__global__ __launch_bounds__(256) void elu_k(float* __restrict__ p, int total) {
    int i = blockIdx.x * 256 + threadIdx.x;
    if (i < total) {
        float t = p[i];
        p[i] = t > 0.0f ? t : expm1f(t);
    }
}

// ===================================================================
// host
// ===================================================================

template<int Fin, int Fout>
static void run_layer_new(const float* hin, float* hout,
                          const float* W, const float* root, const float* bias,
                          const int* oSrc, const int* oDst, const uint2* oF3,
                          const int* octbase, const int* rowptr, float* m,
                          int chunk, hipStream_t stream) {
    const int GN = (N_NODES + 255) / 256;
    if (Fout <= chunk) {
        msg_k<Fin, Fout, Fout><<<GRID_E, 256, 0, stream>>>(hin, oSrc, oDst, oF3, octbase, W, m, 0);
        gather_k<Fin, Fout, Fout><<<GN, 256, 0, stream>>>(hin, m, rowptr, root, bias, hout, 0);
        return;
    }
    if constexpr (Fout > 16) {
        if (chunk == 16) {
            for (int p = 0; p < Fout / 16; ++p) {
                msg_k<Fin, Fout, 16><<<GRID_E, 256, 0, stream>>>(hin, oSrc, oDst, oF3, octbase, W, m, 16 * p);
                gather_k<Fin, Fout, 16><<<GN, 256, 0, stream>>>(hin, m, rowptr, root, bias, hout, 16 * p);
            }
            return;
        }
    }
    if constexpr (Fout > 8) {
        if (chunk == 8) {
            for (int p = 0; p < Fout / 8; ++p) {
                msg_k<Fin, Fout, 8><<<GRID_E, 256, 0, stream>>>(hin, oSrc, oDst, oF3, octbase, W, m, 8 * p);
                gather_k<Fin, Fout, 8><<<GN, 256, 0, stream>>>(hin, m, rowptr, root, bias, hout, 8 * p);
            }
            return;
        }
    }
    if constexpr (Fout > 4) {
        if (chunk == 4) {
            for (int p = 0; p < Fout / 4; ++p) {
                msg_k<Fin, Fout, 4><<<GRID_E, 256, 0, stream>>>(hin, oSrc, oDst, oF3, octbase, W, m, 4 * p);
                gather_k<Fin, Fout, 4><<<GN, 256, 0, stream>>>(hin, m, rowptr, root, bias, hout, 4 * p);
            }
            return;
        }
    }
    if constexpr (Fout > 2) {
        if (chunk == 2) {
            for (int p = 0; p < Fout / 2; ++p) {
                msg_k<Fin, Fout, 2><<<GRID_E, 256, 0, stream>>>(hin, oSrc, oDst, oF3, octbase, W, m, 2 * p);
                gather_k<Fin, Fout, 2><<<GN, 256, 0, stream>>>(hin, m, rowptr, root, bias, hout, 2 * p);
            }
            return;
        }
    }
}

template<int Fin, int Fout>
static void run_layer_old(const float* hin, float* hout,
                          const float* W, const float* root, const float* bias,
                          const int* src, const int* dst, const float* pseudo,
                          hipStream_t stream) {
    init_out_k<Fin, Fout><<<(N_NODES + 255) / 256, 256, 0, stream>>>(hin, root, bias, hout);
    edge_k<Fin, Fout><<<(N_EDGES + 255) / 256, 256, 0, stream>>>(hin, src, dst, pseudo, W, hout);
    int total = N_NODES * Fout;
    elu_k<<<(total + 255) / 256, 256, 0, stream>>>(hout, total);
}

extern "C" void kernel_launch(void* const* d_in, const int* in_sizes, int n_in,
                              void* d_out, int out_size, void* d_ws, size_t ws_size,
                              hipStream_t stream) {
    const float* x      = (const float*)d_in[0];
    const int*   ei     = (const int*)d_in[1];
    const float* pseudo = (const float*)d_in[2];
    const int* src = ei;
    const int* dst = ei + N_EDGES;

    const float* W[6]; const float* R[6]; const float* B[6];
    for (int i = 0; i < 6; ++i) {
        W[i] = (const float*)d_in[3 + 3 * i];
        R[i] = (const float*)d_in[4 + 3 * i];
        B[i] = (const float*)d_in[5 + 3 * i];
    }
    float* out = (float*)d_out;
    char* ws = (char*)d_ws;

    // ---- pick the largest output-chunk whose workspace fits ----
    const int tiers[5] = {32, 16, 8, 4, 2};
    int chunk = 0;
    size_t o_hA = 0, o_hB = 0, o_rp = 0, o_meta = 0, o_ob = 0, o_src = 0, o_dst = 0, o_f3 = 0, o_m = 0;
    for (int t = 0; t < 5; ++t) {
        int c = tiers[t];
        size_t off = 0;
        auto alloc = [&](size_t bytes) { size_t cur = off; off = (off + bytes + 255) & ~(size_t)255; return cur; };
        size_t a_hA   = alloc((size_t)N_NODES * 32 * 4);
        size_t a_hB   = alloc((size_t)N_NODES * 32 * 4);
        size_t a_rp   = alloc((size_t)(N_NODES + 1) * 4);
        size_t a_meta = alloc((size_t)(2 * N_NODES + 16) * 4);
        size_t a_ob   = alloc(9 * 4);
        size_t a_src  = alloc((size_t)E_PAD * 4);
        size_t a_dst  = alloc((size_t)E_PAD * 4);
        size_t a_f3   = alloc((size_t)E_PAD * 8);
        size_t a_m    = alloc((size_t)(E_PAD + 1) * c * 4);
        if (off <= ws_size) {
            chunk = c;
            o_hA = a_hA; o_hB = a_hB; o_rp = a_rp; o_meta = a_meta; o_ob = a_ob;
            o_src = a_src; o_dst = a_dst; o_f3 = a_f3; o_m = a_m;
            break;
        }
    }

    if (chunk > 0) {
        float* hA     = (float*)(ws + o_hA);
        float* hB     = (float*)(ws + o_hB);
        int*   rowptr = (int*)(ws + o_rp);
        int*   cnt    = (int*)(ws + o_meta);
        int*   cnt2   = cnt + N_NODES;
        int*   octcnt = cnt2 + N_NODES;
        int*   octoff = octcnt + 8;
        int*   octbase= (int*)(ws + o_ob);
        int*   oSrc   = (int*)(ws + o_src);
        int*   oDst   = (int*)(ws + o_dst);
        uint2* oF3    = (uint2*)(ws + o_f3);
        float* m      = (float*)(ws + o_m);

        hipMemsetAsync(cnt, 0, (size_t)(2 * N_NODES + 16) * 4, stream);
        hipMemsetAsync(ws + o_src, 0, (o_f3 + (size_t)E_PAD * 8) - o_src, stream);

        count_k<<<N_EDGES / 256, 256, 0, stream>>>(dst, pseudo, cnt, octcnt);
        scan_k<<<1, 1024, 0, stream>>>(cnt, rowptr, octcnt, octbase);
        scatter_k<<<N_EDGES / 256, 256, 0, stream>>>(src, dst, pseudo, rowptr, cnt2,
                                                     octbase, octoff, oSrc, oDst, oF3);

        run_layer_new<1, 8>  (x,  hA, W[0], R[0], B[0], oSrc, oDst, oF3, octbase, rowptr, m, chunk, stream);
        run_layer_new<8, 16> (hA, hB, W[1], R[1], B[1], oSrc, oDst, oF3, octbase, rowptr, m, chunk, stream);
        run_layer_new<16, 32>(hB, hA, W[2], R[2], B[2], oSrc, oDst, oF3, octbase, rowptr, m, chunk, stream);
        run_layer_new<32, 16>(hA, hB, W[3], R[3], B[3], oSrc, oDst, oF3, octbase, rowptr, m, chunk, stream);
        run_layer_new<16, 8> (hB, hA, W[4], R[4], B[4], oSrc, oDst, oF3, octbase, rowptr, m, chunk, stream);
        run_layer_new<8, 1>  (hA, out, W[5], R[5], B[5], oSrc, oDst, oF3, octbase, rowptr, m, chunk, stream);
    } else {
        float* hA = (float*)ws;
        float* hB = hA + (size_t)N_NODES * 32;
        run_layer_old<1, 8>  (x,  hA, W[0], R[0], B[0], src, dst, pseudo, stream);
        run_layer_old<8, 16> (hA, hB, W[1], R[1], B[1], src, dst, pseudo, stream);
        run_layer_old<16, 32>(hB, hA, W[2], R[2], B[2], src, dst, pseudo, stream);
        run_layer_old<32, 16>(hA, hB, W[3], R[3], B[3], src, dst, pseudo, stream);
        run_layer_old<16, 8> (hB, hA, W[4], R[4], B[4], src, dst, pseudo, stream);
        run_layer_old<8, 1>  (hA, out, W[5], R[5], B[5], src, dst, pseudo, stream);
    }
}